// Round 7
// baseline (2309.143 us; speedup 1.0000x reference)
//
#include <hip/hip_runtime.h>
#include <hip/hip_fp16.h>

#define B_ 256
#define T_ 1200
#define I_ 16
#define H_ 128

typedef __attribute__((ext_vector_type(2))) _Float16 h2;
typedef __attribute__((ext_vector_type(4))) _Float16 f16x4;
typedef __attribute__((ext_vector_type(8))) _Float16 f16x8;

union f16x8u { f16x8 v; h2 h[4]; };
union f16x4u { f16x4 v; h2 h[2]; };

__device__ __forceinline__ float fdot2(h2 a, h2 b, float c) {
  return __builtin_amdgcn_fdot2(a, b, c, false);  // v_dot2_f32_f16
}

// Sum across the 4 lanes of a quad (tid&3), broadcast. HW-proven DPP stages.
__device__ __forceinline__ float qsum4(float x) {
  x += __int_as_float(__builtin_amdgcn_update_dpp(0, __float_as_int(x), 0xB1, 0xF, 0xF, true)); // xor 1
  x += __int_as_float(__builtin_amdgcn_update_dpp(0, __float_as_int(x), 0x4E, 0xF, 0xF, true)); // xor 2
  return x;
}

__device__ __forceinline__ float sigm(float x) {
  return __builtin_amdgcn_rcpf(1.f + __expf(-x));
}
__device__ __forceinline__ float tanh_(float x) {
  return 1.f - 2.f * __builtin_amdgcn_rcpf(1.f + __expf(2.f * x));
}

// ============================================================================
// DESIGN (round 7): the compiler hard-caps VGPRs at 128/thread (512thr) and
// 64/thread (1024thr) on this toolchain — measured rounds 0-6; every fused
// variant spilled its 192-reg weight set to scratch (WRITE_SIZE == exactly
// thread_count*192*4B every round). Fix: split so each kernel holds ONE
// 512x128 matrix (64 regs) and fits the budget with headroom.
//   k1 lstm_l0: layer-0 recurrence (W_hh0) -> h0[B,T,H] fp16 in ws
//   k2 lstm_zp: z = W_ih1 @ h0 — recurrence-free, t-parallel (W_ih1)
//   k3 lstm_l1: layer-1 recurrence (W_hh1) + z + linear head -> out
// T is chunked (z-chunk kept L3-resident between k2/k3); h1/c1 state carried
// in ws across chunk launches. Falls back to the proven fused kernel if
// ws_size is too small.
// ============================================================================

// ---------------- k1: layer-0 recurrence ----------------
__global__ __launch_bounds__(512, 1) void lstm_l0(
    const float* __restrict__ xin,
    const float* __restrict__ Wih0, const float* __restrict__ Whh0,
    const float* __restrict__ bih0, const float* __restrict__ bhh0,
    __half* __restrict__ h0g)
{
  __shared__ __align__(16) __half buf0[2][H_];
  const int tid = threadIdx.x;
  const int c = tid & 3;
  const int j = tid >> 2;
  const int b = blockIdx.x;

  h2 w0[4][16], wx[4][2];
  float bs0[4];
#pragma unroll
  for (int q = 0; q < 4; ++q) {
    const int g = q * H_ + j;
    const float* p0 = Whh0 + g * H_ + c * 32;
#pragma unroll
    for (int i = 0; i < 8; ++i) {
      float4 v = *(const float4*)(p0 + 4 * i);
      w0[q][2*i].x   = (_Float16)v.x; w0[q][2*i].y   = (_Float16)v.y;
      w0[q][2*i+1].x = (_Float16)v.z; w0[q][2*i+1].y = (_Float16)v.w;
    }
    const float4 vx = *(const float4*)(Wih0 + g * I_ + 4 * c);
    wx[q][0].x = (_Float16)vx.x; wx[q][0].y = (_Float16)vx.y;
    wx[q][1].x = (_Float16)vx.z; wx[q][1].y = (_Float16)vx.w;
    bs0[q] = (bih0[g] + bhh0[g]) * 0.25f;  // /4: qsum4 restores full bias
  }
  if (tid < H_) {
    const __half z = __float2half(0.f);
    buf0[0][tid] = z; buf0[1][tid] = z;
  }
  float cst0 = 0.f;
  const float* xp = xin + (size_t)b * T_ * I_ + 4 * c;
  __half* hp = h0g + (size_t)b * T_ * H_;
  __syncthreads();

  for (int t = 0; t < T_; ++t) {
    const int rb = t & 1;
    const float4 xv = *(const float4*)xp; xp += I_;
    float a0 = bs0[0], a1 = bs0[1], a2 = bs0[2], a3 = bs0[3];
    const __half* h0p = &buf0[rb ^ 1][c * 32];
#pragma unroll
    for (int i = 0; i < 4; ++i) {
      f16x8u u; u.v = *(const f16x8*)(h0p + 8 * i);
#pragma unroll
      for (int p = 0; p < 4; ++p) {
        const h2 hv = u.h[p];
        const int w = 4 * i + p;
        a0 = fdot2(w0[0][w], hv, a0);
        a1 = fdot2(w0[1][w], hv, a1);
        a2 = fdot2(w0[2][w], hv, a2);
        a3 = fdot2(w0[3][w], hv, a3);
      }
    }
    h2 xa, xb;
    xa.x = (_Float16)xv.x; xa.y = (_Float16)xv.y;
    xb.x = (_Float16)xv.z; xb.y = (_Float16)xv.w;
    a0 = fdot2(wx[0][0], xa, fdot2(wx[0][1], xb, a0));
    a1 = fdot2(wx[1][0], xa, fdot2(wx[1][1], xb, a1));
    a2 = fdot2(wx[2][0], xa, fdot2(wx[2][1], xb, a2));
    a3 = fdot2(wx[3][0], xa, fdot2(wx[3][1], xb, a3));
    const float g0 = qsum4(a0), g1 = qsum4(a1), g2 = qsum4(a2), g3 = qsum4(a3);
    const float ig = sigm(g0), fg = sigm(g1), gg = tanh_(g2), og = sigm(g3);
    cst0 = fg * cst0 + ig * gg;
    const float h0v = og * tanh_(cst0);
    if (c == 0) {
      const __half hh = __float2half(h0v);
      buf0[rb][j] = hh;
      hp[t * H_ + j] = hh;
    }
    __syncthreads();
  }
}

// ---------------- k2: z = W_ih1 @ h0 (recurrence-free) ----------------
// grid = 2*B_: blockIdx = (b<<1)|part; each block does half the chunk's t.
__global__ __launch_bounds__(512, 1) void lstm_zp(
    const __half* __restrict__ h0g, const float* __restrict__ Wih1,
    __half* __restrict__ zg, int t0, int t1, int Tc)
{
  const int tid = threadIdx.x;
  const int c = tid & 3;
  const int j = tid >> 2;
  const int b = blockIdx.x >> 1;
  const int part = blockIdx.x & 1;
  const int th = (t1 - t0) >> 1;
  const int tp0 = t0 + part * th, tp1 = tp0 + th;

  h2 wi[4][16];
#pragma unroll
  for (int q = 0; q < 4; ++q) {
    const float* p1 = Wih1 + (q * H_ + j) * H_ + c * 32;
#pragma unroll
    for (int i = 0; i < 8; ++i) {
      float4 v = *(const float4*)(p1 + 4 * i);
      wi[q][2*i].x   = (_Float16)v.x; wi[q][2*i].y   = (_Float16)v.y;
      wi[q][2*i+1].x = (_Float16)v.z; wi[q][2*i+1].y = (_Float16)v.w;
    }
  }
  const __half* hp = h0g + (size_t)b * T_ * H_ + c * 32;
  // z layout [b][t-t0][j][gate]: lane writes halfs at index == tid ->
  // each wave stores 128B contiguous; k3 reads f16x4 per quad (broadcast).
  __half* zp = zg + (size_t)b * Tc * (4 * H_) + tid;

#pragma unroll 2
  for (int t = tp0; t < tp1; ++t) {
    const __half* hq = hp + (size_t)t * H_;
    float a0 = 0.f, a1 = 0.f, a2 = 0.f, a3 = 0.f;
#pragma unroll
    for (int i = 0; i < 4; ++i) {
      f16x8u u; u.v = *(const f16x8*)(hq + 8 * i);
#pragma unroll
      for (int p = 0; p < 4; ++p) {
        const h2 hv = u.h[p];
        const int w = 4 * i + p;
        a0 = fdot2(wi[0][w], hv, a0);
        a1 = fdot2(wi[1][w], hv, a1);
        a2 = fdot2(wi[2][w], hv, a2);
        a3 = fdot2(wi[3][w], hv, a3);
      }
    }
    a0 = qsum4(a0); a1 = qsum4(a1); a2 = qsum4(a2); a3 = qsum4(a3);
    const float v = (c == 0) ? a0 : ((c == 1) ? a1 : ((c == 2) ? a2 : a3));
    zp[(size_t)(t - t0) * (4 * H_)] = __float2half(v);
  }
}

// ---------------- k3: layer-1 recurrence + head ----------------
__global__ __launch_bounds__(512, 1) void lstm_l1(
    const __half* __restrict__ zg, const float* __restrict__ Whh1,
    const float* __restrict__ bih1, const float* __restrict__ bhh1,
    const float* __restrict__ Wlin, const float* __restrict__ blin,
    __half* __restrict__ h1s, float* __restrict__ c1s,
    float* __restrict__ out, int t0, int t1, int Tc, int first)
{
  __shared__ __align__(16) __half buf1[2][H_];
  __shared__ __align__(16) float red[2][8];
  const int tid = threadIdx.x;
  const int c = tid & 3;
  const int j = tid >> 2;
  const int b = blockIdx.x;
  const int wv = tid >> 6;

  h2 wh[4][16];
  float bs1[4];
#pragma unroll
  for (int q = 0; q < 4; ++q) {
    const int g = q * H_ + j;
    const float* p2 = Whh1 + g * H_ + c * 32;
#pragma unroll
    for (int i = 0; i < 8; ++i) {
      float4 v = *(const float4*)(p2 + 4 * i);
      wh[q][2*i].x   = (_Float16)v.x; wh[q][2*i].y   = (_Float16)v.y;
      wh[q][2*i+1].x = (_Float16)v.z; wh[q][2*i+1].y = (_Float16)v.w;
    }
    bs1[q] = (bih1[g] + bhh1[g]) * 0.25f;
  }
  const float wl = Wlin[j];  // head counts each quad once: no redundancy scale
  const float bl = blin[0];

  const int rs = (t0 & 1) ^ 1;  // slot holding h1(t0-1)
  if (tid < H_) {
    buf1[rs][tid] = first ? __float2half(0.f) : h1s[(size_t)b * H_ + tid];
    buf1[rs ^ 1][tid] = __float2half(0.f);
  }
  float cst1 = first ? 0.f : c1s[(size_t)b * H_ + j];
  const __half* zp = zg + (size_t)b * Tc * (4 * H_) + 4 * j;
  float* op = out + (size_t)b * T_;
  __syncthreads();

  f16x4u zc; zc.v = *(const f16x4*)zp;  // z(t0)
  for (int t = t0; t < t1; ++t) {
    const int rb = t & 1;
    const int tn = (t + 1 < t1) ? (t + 1 - t0) : (t - t0);
    f16x4u zn; zn.v = *(const f16x4*)(zp + (size_t)tn * (4 * H_));  // prefetch

    float b0 = bs1[0], b1 = bs1[1], b2 = bs1[2], b3 = bs1[3];
    const __half* h1p = &buf1[rb ^ 1][c * 32];
#pragma unroll
    for (int i = 0; i < 4; ++i) {
      f16x8u u; u.v = *(const f16x8*)(h1p + 8 * i);
#pragma unroll
      for (int p = 0; p < 4; ++p) {
        const h2 hv = u.h[p];
        const int w = 4 * i + p;
        b0 = fdot2(wh[0][w], hv, b0);
        b1 = fdot2(wh[1][w], hv, b1);
        b2 = fdot2(wh[2][w], hv, b2);
        b3 = fdot2(wh[3][w], hv, b3);
      }
    }
    const float g0 = qsum4(b0) + (float)zc.h[0].x;
    const float g1 = qsum4(b1) + (float)zc.h[0].y;
    const float g2 = qsum4(b2) + (float)zc.h[1].x;
    const float g3 = qsum4(b3) + (float)zc.h[1].y;
    const float ig = sigm(g0), fg = sigm(g1), gg = tanh_(g2), og = sigm(g3);
    cst1 = fg * cst1 + ig * gg;
    const float h1v = og * tanh_(cst1);
    if (c == 0) buf1[rb][j] = __float2half(h1v);
    // head: quad-uniform val; xor4/8/16/32 counts each of 16 quads once
    float val = fmaxf(h1v, 0.f) * wl;
    val += __shfl_xor(val, 4);
    val += __shfl_xor(val, 8);
    val += __shfl_xor(val, 16);
    val += __shfl_xor(val, 32);
    if ((tid & 63) == 0) red[rb][wv] = val;
    zc = zn;
    __syncthreads();
    // read red[rb] after the barrier; next write to red[rb] is at t+2,
    // separated from this read by the t+1 barrier. Rotate the reader.
    if (tid == ((t & 7) << 6)) {
      const float4 r0 = *(const float4*)(&red[rb][0]);
      const float4 r1 = *(const float4*)(&red[rb][4]);
      op[t] = bl + r0.x + r0.y + r0.z + r0.w + r1.x + r1.y + r1.z + r1.w;
    }
  }
  if (c == 0) {  // carry state to next chunk (post-loop barrier already done)
    h1s[(size_t)b * H_ + j] = buf1[(t1 - 1) & 1][j];
    c1s[(size_t)b * H_ + j] = cst1;
  }
}

// ---------------- fallback: round-6 fused kernel (proven, 2259us) ----------
__global__ __launch_bounds__(512, 1) void lstm_fb(
    const float* __restrict__ xin,
    const float* __restrict__ Wih0, const float* __restrict__ Whh0,
    const float* __restrict__ bih0, const float* __restrict__ bhh0,
    const float* __restrict__ Wih1, const float* __restrict__ Whh1,
    const float* __restrict__ bih1, const float* __restrict__ bhh1,
    const float* __restrict__ Wlin, const float* __restrict__ blin,
    float* __restrict__ out)
{
  __shared__ __align__(16) __half buf0[2][H_];
  __shared__ __align__(16) __half buf1[2][H_];
  __shared__ __align__(16) float red[2][8];
  const int tid = threadIdx.x;
  const int c = tid & 3;
  const int j = tid >> 2;
  const int b = blockIdx.x;
  const int wv = tid >> 6;
  h2 w0[4][16], wi[4][16], wh[4][16], wx[4][2];
  float bs0[4], bs1[4];
#pragma unroll
  for (int q = 0; q < 4; ++q) {
    const int g = q * H_ + j;
    const float* p0 = Whh0 + g * H_ + c * 32;
    const float* p1 = Wih1 + g * H_ + c * 32;
    const float* p2 = Whh1 + g * H_ + c * 32;
#pragma unroll
    for (int i = 0; i < 8; ++i) {
      float4 v = *(const float4*)(p0 + 4 * i);
      w0[q][2*i].x   = (_Float16)v.x; w0[q][2*i].y   = (_Float16)v.y;
      w0[q][2*i+1].x = (_Float16)v.z; w0[q][2*i+1].y = (_Float16)v.w;
      v = *(const float4*)(p1 + 4 * i);
      wi[q][2*i].x   = (_Float16)v.x; wi[q][2*i].y   = (_Float16)v.y;
      wi[q][2*i+1].x = (_Float16)v.z; wi[q][2*i+1].y = (_Float16)v.w;
      v = *(const float4*)(p2 + 4 * i);
      wh[q][2*i].x   = (_Float16)v.x; wh[q][2*i].y   = (_Float16)v.y;
      wh[q][2*i+1].x = (_Float16)v.z; wh[q][2*i+1].y = (_Float16)v.w;
    }
    const float4 vx = *(const float4*)(Wih0 + g * I_ + 4 * c);
    wx[q][0].x = (_Float16)vx.x; wx[q][0].y = (_Float16)vx.y;
    wx[q][1].x = (_Float16)vx.z; wx[q][1].y = (_Float16)vx.w;
    bs0[q] = (bih0[g] + bhh0[g]) * 0.25f;
    bs1[q] = (bih1[g] + bhh1[g]) * 0.25f;
  }
  const float wl = Wlin[j];
  const float bl = blin[0];
  if (tid < H_) {
    const __half z = __float2half(0.f);
    buf0[0][tid] = z; buf0[1][tid] = z;
    buf1[0][tid] = z; buf1[1][tid] = z;
  }
  float cst0 = 0.f, cst1 = 0.f;
  const float* xp = xin + b * (T_ * I_) + 4 * c;
  __syncthreads();
  for (int t = 0; t <= T_; ++t) {
    const int rb = t & 1;
    if (t >= 2 && tid == (((t - 2) & 7) << 6)) {
      const float4 r0 = *(const float4*)(&red[rb ^ 1][0]);
      const float4 r1 = *(const float4*)(&red[rb ^ 1][4]);
      out[b * T_ + (t - 2)] = bl +
          r0.x + r0.y + r0.z + r0.w + r1.x + r1.y + r1.z + r1.w;
    }
    float4 xv = make_float4(0.f, 0.f, 0.f, 0.f);
    if (t < T_) { xv = *(const float4*)xp; xp += I_; }
    float a0 = bs0[0], a1 = bs0[1], a2 = bs0[2], a3 = bs0[3];
    float b0 = bs1[0], b1 = bs1[1], b2 = bs1[2], b3 = bs1[3];
    const __half* h0p = &buf0[rb ^ 1][c * 32];
    const __half* h1p = &buf1[rb][c * 32];
#pragma unroll
    for (int i = 0; i < 4; ++i) {
      f16x8u u; u.v = *(const f16x8*)(h0p + 8 * i);
#pragma unroll
      for (int p = 0; p < 4; ++p) {
        const h2 hv = u.h[p];
        const int w = 4 * i + p;
        a0 = fdot2(w0[0][w], hv, a0);
        a1 = fdot2(w0[1][w], hv, a1);
        a2 = fdot2(w0[2][w], hv, a2);
        a3 = fdot2(w0[3][w], hv, a3);
        b0 = fdot2(wi[0][w], hv, b0);
        b1 = fdot2(wi[1][w], hv, b1);
        b2 = fdot2(wi[2][w], hv, b2);
        b3 = fdot2(wi[3][w], hv, b3);
      }
    }
#pragma unroll
    for (int i = 0; i < 4; ++i) {
      f16x8u u; u.v = *(const f16x8*)(h1p + 8 * i);
#pragma unroll
      for (int p = 0; p < 4; ++p) {
        const h2 hv = u.h[p];
        const int w = 4 * i + p;
        b0 = fdot2(wh[0][w], hv, b0);
        b1 = fdot2(wh[1][w], hv, b1);
        b2 = fdot2(wh[2][w], hv, b2);
        b3 = fdot2(wh[3][w], hv, b3);
      }
    }
    h2 xa, xb;
    xa.x = (_Float16)xv.x; xa.y = (_Float16)xv.y;
    xb.x = (_Float16)xv.z; xb.y = (_Float16)xv.w;
    a0 = fdot2(wx[0][0], xa, fdot2(wx[0][1], xb, a0));
    a1 = fdot2(wx[1][0], xa, fdot2(wx[1][1], xb, a1));
    a2 = fdot2(wx[2][0], xa, fdot2(wx[2][1], xb, a2));
    a3 = fdot2(wx[3][0], xa, fdot2(wx[3][1], xb, a3));
    if (t < T_) {
      const float g0 = qsum4(a0), g1 = qsum4(a1), g2 = qsum4(a2), g3 = qsum4(a3);
      const float ig = sigm(g0), fg = sigm(g1), gg = tanh_(g2), og = sigm(g3);
      cst0 = fg * cst0 + ig * gg;
      const float h0v = og * tanh_(cst0);
      if (c == 0) buf0[rb][j] = __float2half(h0v);
    }
    if (t >= 1) {
      const float g0 = qsum4(b0), g1 = qsum4(b1), g2 = qsum4(b2), g3 = qsum4(b3);
      const float ig = sigm(g0), fg = sigm(g1), gg = tanh_(g2), og = sigm(g3);
      cst1 = fg * cst1 + ig * gg;
      const float h1v = og * tanh_(cst1);
      if (c == 0) buf1[rb ^ 1][j] = __float2half(h1v);
      float val = fmaxf(h1v, 0.f) * wl;
      val += __shfl_xor(val, 4);
      val += __shfl_xor(val, 8);
      val += __shfl_xor(val, 16);
      val += __shfl_xor(val, 32);
      if ((tid & 63) == 0) red[rb][wv] = val;
    }
    __syncthreads();
  }
  if (tid == 0) {
    const int s = T_ & 1;
    const float4 r0 = *(const float4*)(&red[s][0]);
    const float4 r1 = *(const float4*)(&red[s][4]);
    out[b * T_ + (T_ - 1)] = bl +
        r0.x + r0.y + r0.z + r0.w + r1.x + r1.y + r1.z + r1.w;
  }
}

extern "C" void kernel_launch(void* const* d_in, const int* in_sizes, int n_in,
                              void* d_out, int out_size, void* d_ws, size_t ws_size,
                              hipStream_t stream) {
  const float* xin  = (const float*)d_in[0];
  const float* Wih0 = (const float*)d_in[1];
  const float* Whh0 = (const float*)d_in[2];
  const float* bih0 = (const float*)d_in[3];
  const float* bhh0 = (const float*)d_in[4];
  const float* Wih1 = (const float*)d_in[5];
  const float* Whh1 = (const float*)d_in[6];
  const float* bih1 = (const float*)d_in[7];
  const float* bhh1 = (const float*)d_in[8];
  const float* Wlin = (const float*)d_in[9];
  const float* blin = (const float*)d_in[10];
  float* out = (float*)d_out;

  const size_t h0_bytes = (size_t)B_ * T_ * H_ * 2;            // 78,643,200
  const size_t h1s_bytes = (size_t)B_ * H_ * 2;
  const size_t c1s_bytes = (size_t)B_ * H_ * 4;
  const size_t st_bytes = h1s_bytes + c1s_bytes;

  int nc = 0;  // prefer 4 (z-chunk 78MB, L3-resident); 8 if ws is tight
  if (d_ws) {
    if (ws_size >= h0_bytes + st_bytes + (size_t)B_ * (T_ / 4) * 4 * H_ * 2) nc = 4;
    else if (ws_size >= h0_bytes + st_bytes + (size_t)B_ * (T_ / 8) * 4 * H_ * 2) nc = 8;
  }
  if (!nc) {  // workspace too small: proven fused fallback
    lstm_fb<<<B_, 512, 0, stream>>>(xin, Wih0, Whh0, bih0, bhh0,
                                    Wih1, Whh1, bih1, bhh1, Wlin, blin, out);
    return;
  }

  char* ws = (char*)d_ws;
  __half* h0g = (__half*)ws;
  __half* h1s = (__half*)(ws + h0_bytes);
  float*  c1s = (float*)(ws + h0_bytes + h1s_bytes);
  __half* zg  = (__half*)(ws + h0_bytes + st_bytes);
  const int Tc = T_ / nc;

  lstm_l0<<<B_, 512, 0, stream>>>(xin, Wih0, Whh0, bih0, bhh0, h0g);
  for (int ci = 0; ci < nc; ++ci) {
    const int t0 = ci * Tc, t1 = t0 + Tc;
    lstm_zp<<<B_ * 2, 512, 0, stream>>>(h0g, Wih1, zg, t0, t1, Tc);
    lstm_l1<<<B_, 512, 0, stream>>>(zg, Whh1, bih1, bhh1, Wlin, blin,
                                    h1s, c1s, out, t0, t1, Tc, ci == 0 ? 1 : 0);
  }
}